// Round 1
// baseline (141.031 us; speedup 1.0000x reference)
//
#include <hip/hip_runtime.h>

// Who2com collapses analytically:
//   final[b,:,q] is a softmax distribution (over the compacted key dim) with a
//   zero re-inserted on the diagonal -> sum_k final[b,k,q] == 1 exactly.
//   val_mat[b,k,q] = bevs[b,q]  (key-independent)
//   => feat_fuse[b,q] = bevs[b,q];  out = mean over q = (1/N) * sum_q bevs[b,q].
// The conv stack / MLPs / attention only set the softmax values, which cancel
// in the column sum. So the kernel is a pure memory-bound 5-way mean:
//   out[b,c,h,w] = 0.2 * sum_{q=0..4} bevs[b,q,c,h,w]
//
// Sizes: B=32, N=5, C=256, H=W=16 -> CHW = 65536 floats per (b,q) slice.
// Read 40 MB + write 8 MB -> ~7.6 us at 6.3 TB/s.

static constexpr int B_   = 32;
static constexpr int N_   = 5;
static constexpr int CHW  = 256 * 16 * 16;      // 65536
static constexpr int CHW4 = CHW / 4;            // 16384 float4 per slice

__global__ __launch_bounds__(256) void who2com_mean_kernel(
    const float4* __restrict__ bevs, float4* __restrict__ out) {
    const int idx = blockIdx.x * blockDim.x + threadIdx.x;   // [0, B_*CHW4)
    const int b = idx >> 14;          // idx / CHW4  (CHW4 = 2^14)
    const int r = idx & (CHW4 - 1);   // idx % CHW4

    const float4* base = bevs + (size_t)b * N_ * CHW4 + r;
    float4 acc = base[0];
    float4 v1 = base[1 * CHW4];
    float4 v2 = base[2 * CHW4];
    float4 v3 = base[3 * CHW4];
    float4 v4 = base[4 * CHW4];
    acc.x += v1.x; acc.y += v1.y; acc.z += v1.z; acc.w += v1.w;
    acc.x += v2.x; acc.y += v2.y; acc.z += v2.z; acc.w += v2.w;
    acc.x += v3.x; acc.y += v3.y; acc.z += v3.z; acc.w += v3.w;
    acc.x += v4.x; acc.y += v4.y; acc.z += v4.z; acc.w += v4.w;

    const float inv = 1.0f / (float)N_;
    acc.x *= inv; acc.y *= inv; acc.z *= inv; acc.w *= inv;
    out[idx] = acc;
}

extern "C" void kernel_launch(void* const* d_in, const int* in_sizes, int n_in,
                              void* d_out, int out_size, void* d_ws, size_t ws_size,
                              hipStream_t stream) {
    (void)in_sizes; (void)n_in; (void)d_ws; (void)ws_size; (void)out_size;
    const float4* bevs = (const float4*)d_in[0];   // (B, N, C, H, W) fp32
    float4* out = (float4*)d_out;                  // (B, C, H, W) fp32

    const int total4 = B_ * CHW4;                  // 524288 float4 outputs
    const int block = 256;
    const int grid = total4 / block;               // 2048 blocks
    who2com_mean_kernel<<<grid, block, 0, stream>>>(bevs, out);
}